// Round 1
// baseline (280.794 us; speedup 1.0000x reference)
//
#include <hip/hip_runtime.h>

#define TD_ 512
#define B_  32
#define H_  512
#define TE_ 2048

typedef __attribute__((ext_vector_type(8))) short bf16x8;
typedef __attribute__((ext_vector_type(4))) short bf16x4;
typedef __attribute__((ext_vector_type(4))) float f32x4;

__device__ __forceinline__ short f2b(float f){
  union { float f; unsigned u; } v; v.f = f;
  return (short)((v.u + 0x7fffu + ((v.u >> 16) & 1u)) >> 16);  // RNE f32->bf16
}

__device__ __forceinline__ void gload16(const void* g, void* l){
  __builtin_amdgcn_global_load_lds((const __attribute__((address_space(1))) void*)g,
                                   (__attribute__((address_space(3))) void*)l,
                                   16, 0, 0);
}

// outputs_hidden (TD,B,H) f32 -> Abf (B,TD,H) bf16
__global__ __launch_bounds__(256) void k_cvtA(const float* __restrict__ oh,
                                              short* __restrict__ Abf){
  long base = ((long)blockIdx.x * 256 + threadIdx.x) * 4;
  int t = (int)(base >> 14);          // / (B_*H_)
  int rem = (int)(base & 16383);
  int b = rem >> 9, h = rem & 511;
  f32x4 v = *(const f32x4*)(oh + base);
  bf16x4 o;
  o[0]=f2b(v[0]); o[1]=f2b(v[1]); o[2]=f2b(v[2]); o[3]=f2b(v[3]);
  *(bf16x4*)(Abf + (long)b*TD_*H_ + (long)t*H_ + h) = o;
}

// encoder_out (B,H,TE) f32 -> Ebt (B,TE,H) bf16   (32x32 LDS tile transpose)
__global__ __launch_bounds__(256) void k_trE(const float* __restrict__ E,
                                             short* __restrict__ Ebt){
  __shared__ float tile[32][33];
  int b = blockIdx.z;
  int h0 = blockIdx.y << 5, e0 = blockIdx.x << 5;
  int x = threadIdx.x & 31, y = threadIdx.x >> 5;   // y in [0,8)
  const float* Eb = E + (long)b*H_*TE_;
  #pragma unroll
  for (int i=0;i<4;i++)
    tile[y + i*8][x] = Eb[(long)(h0 + y + i*8)*TE_ + e0 + x];
  __syncthreads();
  short* Ob = Ebt + (long)b*TE_*H_;
  #pragma unroll
  for (int i=0;i<4;i++)
    Ob[(long)(e0 + y + i*8)*H_ + h0 + x] = f2b(tile[x][y + i*8]);
}

// GEMM1 + fused epilogue: scores = Abf @ Ebt^T (K=H), then
// ta = exp(score); NS = ta + S (out2); att = ta/S (bf16 ws); rowsum += ta/S
__global__ __launch_bounds__(256) void k_scores(
    const short* __restrict__ Abf, const short* __restrict__ Ebt,
    const float* __restrict__ S, float* __restrict__ NS,
    short* __restrict__ att, float* __restrict__ rs){
  __shared__ short As[128*64];
  __shared__ short Bs[128*64];
  int b = blockIdx.z;
  int t0 = blockIdx.y << 7;
  int e0 = blockIdx.x << 7;
  int tid = threadIdx.x, lane = tid & 63, w = tid >> 6;
  int wr = w >> 1, wc = w & 1, g = lane >> 4, lr = lane & 15;

  const short* Ag = Abf + (long)b*TD_*H_ + (long)t0*H_;
  const short* Bg = Ebt + (long)b*TE_*H_ + (long)e0*H_;

  const f32x4 fzero = {0.f, 0.f, 0.f, 0.f};
  f32x4 acc[4][4];
  #pragma unroll
  for (int m=0;m<4;m++)
    #pragma unroll
    for (int n=0;n<4;n++)
      acc[m][n] = fzero;

  for (int k0=0;k0<H_;k0+=64){
    __syncthreads();
    #pragma unroll
    for (int p=0;p<4;p++){
      int cb = (w*4 + p)*64;        // wave-uniform chunk base (16B chunks)
      int c = cb + lane;
      int row = c >> 3, cc = c & 7;
      gload16(Ag + (long)row*H_ + k0 + cc*8, (char*)As + cb*16);
      gload16(Bg + (long)row*H_ + k0 + cc*8, (char*)Bs + cb*16);
    }
    __syncthreads();
    #pragma unroll
    for (int ks=0;ks<2;ks++){
      bf16x8 af[4], bfr[4];
      #pragma unroll
      for (int m=0;m<4;m++)
        af[m] = *(const bf16x8*)(As + (wr*64 + m*16 + lr)*64 + ks*32 + g*8);
      #pragma unroll
      for (int n=0;n<4;n++)
        bfr[n] = *(const bf16x8*)(Bs + (wc*64 + n*16 + lr)*64 + ks*32 + g*8);
      #pragma unroll
      for (int m=0;m<4;m++)
        #pragma unroll
        for (int n=0;n<4;n++)
          acc[m][n] = __builtin_amdgcn_mfma_f32_16x16x32_bf16(af[m], bfr[n], acc[m][n], 0, 0, 0);
    }
  }

  const float* Sb = S + (long)b*TD_*TE_;
  float* NSb = NS + (long)b*TD_*TE_;
  short* attb = att + (long)b*TD_*TE_;
  #pragma unroll
  for (int m=0;m<4;m++){
    #pragma unroll
    for (int r=0;r<4;r++){
      int t = t0 + wr*64 + m*16 + g*4 + r;
      float rp = 0.f;
      #pragma unroll
      for (int n=0;n<4;n++){
        int e = e0 + wc*64 + n*16 + lr;
        long off = (long)t*TE_ + e;
        float sv = Sb[off];
        float ta = __expf(acc[m][n][r]);
        NSb[off] = ta + sv;
        float av = ta / sv;
        attb[off] = f2b(av);
        rp += av;
      }
      rp += __shfl_xor(rp, 1);
      rp += __shfl_xor(rp, 2);
      rp += __shfl_xor(rp, 4);
      rp += __shfl_xor(rp, 8);
      if (lr == 0) atomicAdd(&rs[b*TD_ + t], rp);
    }
  }
}

// GEMM2: ctx[t,h] = (att[t,:] . E[h,:]) / rowsum[t], K=TE. A=att bf16 (lds-direct),
// B=E f32 reg-staged->bf16. Output written as (TD,B,H).
__global__ __launch_bounds__(256) void k_ctx(
    const short* __restrict__ att, const float* __restrict__ E,
    const float* __restrict__ rs, float* __restrict__ ctx){
  __shared__ short As[128*64];
  __shared__ short Bs[128*64];
  int b = blockIdx.z;
  int t0 = blockIdx.y << 7;
  int h0 = blockIdx.x << 7;
  int tid = threadIdx.x, lane = tid & 63, w = tid >> 6;
  int wr = w >> 1, wc = w & 1, g = lane >> 4, lr = lane & 15;

  const short* Ag = att + (long)b*TD_*TE_ + (long)t0*TE_;
  const float* Bgf = E + (long)b*H_*TE_ + (long)h0*TE_;

  const f32x4 fzero = {0.f, 0.f, 0.f, 0.f};
  f32x4 acc[4][4];
  #pragma unroll
  for (int m=0;m<4;m++)
    #pragma unroll
    for (int n=0;n<4;n++)
      acc[m][n] = fzero;

  for (int k0=0;k0<TE_;k0+=64){
    __syncthreads();
    #pragma unroll
    for (int p=0;p<4;p++){
      int cb = (w*4 + p)*64;
      int c = cb + lane;
      int row = c >> 3, cc = c & 7;
      gload16(Ag + (long)row*TE_ + k0 + cc*8, (char*)As + cb*16);
    }
    #pragma unroll
    for (int p=0;p<8;p++){
      int c = tid + p*256;          // f32x4 chunk index over 128x64 f32 tile
      int row = c >> 4, cc = c & 15;
      f32x4 v = *(const f32x4*)(Bgf + (long)row*TE_ + k0 + cc*4);
      bf16x4 o;
      o[0]=f2b(v[0]); o[1]=f2b(v[1]); o[2]=f2b(v[2]); o[3]=f2b(v[3]);
      *(bf16x4*)(Bs + row*64 + cc*4) = o;
    }
    __syncthreads();
    #pragma unroll
    for (int ks=0;ks<2;ks++){
      bf16x8 af[4], bfr[4];
      #pragma unroll
      for (int m=0;m<4;m++)
        af[m] = *(const bf16x8*)(As + (wr*64 + m*16 + lr)*64 + ks*32 + g*8);
      #pragma unroll
      for (int n=0;n<4;n++)
        bfr[n] = *(const bf16x8*)(Bs + (wc*64 + n*16 + lr)*64 + ks*32 + g*8);
      #pragma unroll
      for (int m=0;m<4;m++)
        #pragma unroll
        for (int n=0;n<4;n++)
          acc[m][n] = __builtin_amdgcn_mfma_f32_16x16x32_bf16(af[m], bfr[n], acc[m][n], 0, 0, 0);
    }
  }

  #pragma unroll
  for (int m=0;m<4;m++){
    #pragma unroll
    for (int r=0;r<4;r++){
      int t = t0 + wr*64 + m*16 + g*4 + r;
      float inv = 1.0f / rs[b*TD_ + t];
      #pragma unroll
      for (int n=0;n<4;n++){
        int h = h0 + wc*64 + n*16 + lr;
        ctx[(long)t*B_*H_ + (long)b*H_ + h] = acc[m][n][r] * inv;
      }
    }
  }
}

extern "C" void kernel_launch(void* const* d_in, const int* in_sizes, int n_in,
                              void* d_out, int out_size, void* d_ws, size_t ws_size,
                              hipStream_t stream){
  const float* oh = (const float*)d_in[0];   // (TD,B,H)
  const float* E  = (const float*)d_in[1];   // (B,H,TE)
  const float* S  = (const float*)d_in[2];   // (B,TD,TE)
  float* out_ctx = (float*)d_out;                       // (TD,B,H)
  float* out_ns  = out_ctx + (long)TD_*B_*H_;           // (B,TD,TE)

  char* ws = (char*)d_ws;
  size_t offA  = 0;
  size_t offEb = offA  + (size_t)B_*TD_*H_*2;    // Abf: 16 MiB
  size_t offAt = offEb + (size_t)B_*TE_*H_*2;    // Ebt: 64 MiB
  size_t offRs = offAt + (size_t)B_*TD_*TE_*2;   // att: 64 MiB
  short* Abf = (short*)(ws + offA);
  short* Ebt = (short*)(ws + offEb);
  short* attw = (short*)(ws + offAt);
  float* rs  = (float*)(ws + offRs);

  hipMemsetAsync(rs, 0, (size_t)B_*TD_*4, stream);
  k_cvtA<<<dim3((TD_*B_*H_)/(256*4)), 256, 0, stream>>>(oh, Abf);
  k_trE<<<dim3(TE_/32, H_/32, B_), 256, 0, stream>>>(E, Ebt);
  k_scores<<<dim3(TE_/128, TD_/128, B_), 256, 0, stream>>>(Abf, Ebt, S, out_ns, attw, rs);
  k_ctx<<<dim3(H_/128, TD_/128, B_), 256, 0, stream>>>(attw, E, rs, out_ctx);
}